// Round 3
// baseline (1395.664 us; speedup 1.0000x reference)
//
#include <hip/hip_runtime.h>
#include <hip/hip_bf16.h>

// FusedMoEWithLoRA: grouped bf16-MFMA GEMMs, m97-style global_load_lds staging.
// LoRA B-matrices folded into GEMM K dim (K += L*R = 64); LoRA A-products
// computed as small MFMA GEMMs (u_all = X.gua^T, masked by adapter in epilogue).

#define E_   8
#define H_   2048
#define I_   1024
#define I2_  2048
#define K_   2
#define L_   4
#define R_   16
#define T_   4096
#define LR_  64
#define BM   128
#define BN   128
#define BK   32
#define MAXPAD 9216
#define KTOT1 (H_ + LR_)   // 2112
#define KTOT2 (I_ + LR_)   // 1088

typedef __attribute__((ext_vector_type(8))) __bf16 bf16x8;
typedef __attribute__((ext_vector_type(4))) float  f32x4;

__device__ __forceinline__ unsigned short f2bf(float f) {
  union { float f; unsigned u; } v; v.f = f;
  unsigned u = v.u;
  u += 0x7fffu + ((u >> 16) & 1u);
  return (unsigned short)(u >> 16);
}
__device__ __forceinline__ unsigned pack2(float a, float b) {
  __hip_bfloat162 h = __float22bfloat162_rn(float2{a, b});
  union { __hip_bfloat162 h; unsigned u; } v; v.h = h;
  return v.u;
}
__device__ __forceinline__ void async16(const void* g, void* l) {
  __builtin_amdgcn_global_load_lds((const __attribute__((address_space(1))) void*)g,
                                   (__attribute__((address_space(3))) void*)l, 16, 0, 0);
}

// ---------------- routing ----------------
__global__ void k_count(const int* __restrict__ topk_ids, int* __restrict__ cnt) {
  int i = blockIdx.x * blockDim.x + threadIdx.x;
  if (i < T_ * K_) atomicAdd(&cnt[topk_ids[i]], 1);
}

__global__ void k_prefix(const int* __restrict__ cnt, int* __restrict__ pad_off) {
  if (threadIdx.x == 0) {
    int off = 0;
    for (int e = 0; e < E_; ++e) {
      pad_off[e] = off;
      off += ((cnt[e] + BM - 1) / BM) * BM;
    }
    pad_off[E_] = off;
  }
}

__global__ void k_scatter(const int* __restrict__ topk_ids, const float* __restrict__ topk_w,
                          const int* __restrict__ tli, const int* __restrict__ pad_off,
                          int* __restrict__ cnt2, int* __restrict__ tok,
                          float* __restrict__ wgt, int* __restrict__ lidx) {
  int i = blockIdx.x * blockDim.x + threadIdx.x;
  if (i < T_ * K_) {
    int e = topk_ids[i];
    int pos = atomicAdd(&cnt2[e], 1);
    int g = pad_off[e] + pos;
    int t = i / K_;
    tok[g] = t;
    wgt[g] = topk_w[i];
    lidx[g] = tli[t];
  }
}

// ---------------- bf16 conversions (K=2048 family): w13 + gub tail, gua ----------------
__global__ void k_cvtA(const float* __restrict__ w13, const float* __restrict__ gub,
                       const float* __restrict__ gua,
                       unsigned short* __restrict__ w13x, unsigned short* __restrict__ gua_x) {
  const int bid = blockIdx.x;
  const int tid = threadIdx.x;
  if (bid < E_ * I2_) {
    const int e = bid >> 11, n = bid & (I2_ - 1);
    const float* src = w13 + (size_t)bid * H_;
    unsigned short* dst = w13x + (size_t)bid * KTOT1;
#pragma unroll
    for (int c = tid; c < H_ / 4; c += 256) {
      float4 f = *(const float4*)(src + c * 4);
      *(uint2*)(dst + c * 4) = make_uint2(pack2(f.x, f.y), pack2(f.z, f.w));
    }
    if (tid < LR_) {
      const int l = tid >> 4, r = tid & 15;
      dst[H_ + tid] = f2bf(gub[(((size_t)l * E_ + e) * I2_ + n) * R_ + r]);
    }
  } else {
    const int idx = bid - E_ * I2_;               // e*64 + (l*16+r)
    const int e = idx >> 6, n = idx & 63;
    const int l = n >> 4, r = n & 15;
    const float* src = gua + (((size_t)l * E_ + e) * R_ + r) * H_;
    unsigned short* dst = gua_x + ((size_t)e * LR_ + n) * H_;
#pragma unroll
    for (int c = tid; c < H_ / 4; c += 256) {
      float4 f = *(const float4*)(src + c * 4);
      *(uint2*)(dst + c * 4) = make_uint2(pack2(f.x, f.y), pack2(f.z, f.w));
    }
  }
}

// ---------------- bf16 conversions (K=1024 family): w2 + dnb tail, dna ----------------
__global__ void k_cvtB(const float* __restrict__ w2, const float* __restrict__ dnb,
                       const float* __restrict__ dna,
                       unsigned short* __restrict__ w2x, unsigned short* __restrict__ dna_x) {
  const int bid = blockIdx.x;
  const int tid = threadIdx.x;
  if (bid < E_ * H_) {
    const int e = bid >> 11, n = bid & (H_ - 1);
    const float* src = w2 + (size_t)bid * I_;
    unsigned short* dst = w2x + (size_t)bid * KTOT2;
    {
      float4 f = *(const float4*)(src + tid * 4);
      *(uint2*)(dst + tid * 4) = make_uint2(pack2(f.x, f.y), pack2(f.z, f.w));
    }
    if (tid < LR_) {
      const int l = tid >> 4, r = tid & 15;
      dst[I_ + tid] = f2bf(dnb[(((size_t)l * E_ + e) * H_ + n) * R_ + r]);
    }
  } else {
    const int idx = bid - E_ * H_;
    const int e = idx >> 6, n = idx & 63;
    const int l = n >> 4, r = n & 15;
    const float* src = dna + (((size_t)l * E_ + e) * R_ + r) * I_;
    unsigned short* dst = dna_x + ((size_t)e * LR_ + n) * I_;
    {
      float4 f = *(const float4*)(src + tid * 4);
      *(uint2*)(dst + tid * 4) = make_uint2(pack2(f.x, f.y), pack2(f.z, f.w));
    }
  }
}

// ---------------- gather hidden rows into routed order (bf16) ----------------
__global__ void k_gather(const float* __restrict__ hidden, const int* __restrict__ tok,
                         const int* __restrict__ pad_off, const int* __restrict__ cnt,
                         unsigned short* __restrict__ x_rt) {
  const int g = blockIdx.x;
  const int tid = threadIdx.x;
  int e = -1;
#pragma unroll
  for (int i = 0; i < E_; ++i)
    if (g >= pad_off[i] && g < pad_off[i + 1]) e = i;
  const bool valid = (e >= 0) && ((g - pad_off[e]) < cnt[e]);
  const int t = valid ? tok[g] : 0;
  const float* src = hidden + (size_t)t * H_;
  unsigned short* dst = x_rt + (size_t)g * KTOT1;
#pragma unroll
  for (int c = tid; c < H_ / 4; c += 256) {
    uint2 v = make_uint2(0u, 0u);
    if (valid) {
      float4 f = *(const float4*)(src + c * 4);
      v = make_uint2(pack2(f.x, f.y), pack2(f.z, f.w));
    }
    *(uint2*)(dst + c * 4) = v;
  }
}

// ---------------- LoRA-A GEMM: strip[g][n] = (n>>4 == lidx[g]) ? X[g]·A[n] : 0 ----------------
// M=128 rows (one expert block), N=64 (l*16+r), K=Kdim. Writes masked strip into
// dst rows at column offset kofs (row stride = rstride).
template <int KDIM, int RSTRIDE, int KOFS>
__global__ __launch_bounds__(256, 4)
void k_lora_gemm(const unsigned short* __restrict__ X, const unsigned short* __restrict__ A,
                 const int* __restrict__ lidx, const int* __restrict__ pad_off,
                 const int* __restrict__ cnt, unsigned short* __restrict__ dst) {
  __shared__ __align__(16) unsigned short sA[BM * BK];   // 8 KB
  __shared__ __align__(16) unsigned short sB[LR_ * BK];  // 4 KB

  const int base = blockIdx.x * BM;
  if (base >= pad_off[E_]) return;
  int e = 0;
#pragma unroll
  for (int i = 1; i < E_; ++i) if (base >= pad_off[i]) e = i;
  const int erow0 = pad_off[e];
  const int cnt_e = cnt[e];

  const int tid  = threadIdx.x;
  const int lane = tid & 63;
  const int wid  = tid >> 6;
  const int wm   = wid * 32;
  const int quad = lane >> 4;
  const int mr   = lane & 15;

  const unsigned short* aS0 = X + (size_t)(base + (tid >> 2)) * RSTRIDE + (tid & 3) * 8;
  const unsigned short* aS1 = aS0 + (size_t)64 * RSTRIDE;
  const unsigned short* bS  = A + ((size_t)e * LR_ + (tid >> 2)) * KDIM + (tid & 3) * 8;
  unsigned short* aD = sA + wid * 512;
  unsigned short* bD = sB + wid * 512;

  f32x4 zero = {0.f, 0.f, 0.f, 0.f};
  f32x4 acc[2][4];
#pragma unroll
  for (int i = 0; i < 2; ++i)
#pragma unroll
    for (int j = 0; j < 4; ++j) acc[i][j] = zero;

  for (int kt = 0; kt < KDIM; kt += BK) {
    async16(aS0, aD);  async16(aS1, aD + 2048);
    async16(bS,  bD);
    aS0 += BK; aS1 += BK; bS += BK;
    __syncthreads();

    bf16x8 af[2], bb[4];
#pragma unroll
    for (int i = 0; i < 2; ++i)
      af[i] = *(const bf16x8*)&sA[(wm + i * 16 + mr) * BK + quad * 8];
#pragma unroll
    for (int j = 0; j < 4; ++j)
      bb[j] = *(const bf16x8*)&sB[(j * 16 + mr) * BK + quad * 8];
#pragma unroll
    for (int i = 0; i < 2; ++i)
#pragma unroll
      for (int j = 0; j < 4; ++j)
        acc[i][j] = __builtin_amdgcn_mfma_f32_16x16x32_bf16(af[i], bb[j], acc[i][j], 0, 0, 0);
    __syncthreads();
  }

  // epilogue: column n = j*16+mr encodes adapter l = j; mask and store strip.
#pragma unroll
  for (int i = 0; i < 2; ++i)
#pragma unroll
    for (int j = 0; j < 4; ++j)
#pragma unroll
      for (int r = 0; r < 4; ++r) {
        const int m = wm + i * 16 + quad * 4 + r;
        const int g = base + m;
        const bool valid = ((g - erow0) < cnt_e) && (lidx[g] == j);
        const float v = valid ? acc[i][j][r] : 0.f;
        dst[(size_t)g * RSTRIDE + KOFS + j * 16 + mr] = f2bf(v);
      }
}

// ---------------- phase 1: gate_up GEMM + SwiGLU ----------------
__global__ __launch_bounds__(256, 4)
void k_gemm1(const unsigned short* __restrict__ x_rt, const unsigned short* __restrict__ w13x,
             const int* __restrict__ pad_off, unsigned short* __restrict__ act) {
  __shared__ __align__(16) unsigned short sA [BM * BK];
  __shared__ __align__(16) unsigned short sBg[BN * BK];
  __shared__ __align__(16) unsigned short sBu[BN * BK];

  const int base = blockIdx.y * BM;
  if (base >= pad_off[E_]) return;
  int e = 0;
#pragma unroll
  for (int i = 1; i < E_; ++i) if (base >= pad_off[i]) e = i;
  const int n0 = blockIdx.x * BN;

  const int tid  = threadIdx.x;
  const int lane = tid & 63;
  const int wid  = tid >> 6;
  const int wm   = (wid >> 1) * 64;
  const int wn   = (wid & 1) * 64;
  const int quad = lane >> 4;
  const int mr   = lane & 15;

  const int srow = tid >> 2, spc = (tid & 3) * 8;
  const unsigned short* aS0  = x_rt + (size_t)(base + srow) * KTOT1 + spc;
  const unsigned short* aS1  = aS0 + (size_t)64 * KTOT1;
  const unsigned short* bgS0 = w13x + ((size_t)e * I2_ + n0 + srow) * KTOT1 + spc;
  const unsigned short* bgS1 = bgS0 + (size_t)64 * KTOT1;
  const unsigned short* buS0 = bgS0 + (size_t)I_ * KTOT1;
  const unsigned short* buS1 = buS0 + (size_t)64 * KTOT1;
  unsigned short* aD  = sA  + wid * 512;
  unsigned short* bgD = sBg + wid * 512;
  unsigned short* buD = sBu + wid * 512;

  f32x4 zero = {0.f, 0.f, 0.f, 0.f};
  f32x4 accg[4][4], accu[4][4];
#pragma unroll
  for (int i = 0; i < 4; ++i)
#pragma unroll
    for (int j = 0; j < 4; ++j) { accg[i][j] = zero; accu[i][j] = zero; }

  for (int kt = 0; kt < KTOT1; kt += BK) {
    async16(aS0,  aD);        async16(aS1,  aD + 2048);
    async16(bgS0, bgD);       async16(bgS1, bgD + 2048);
    async16(buS0, buD);       async16(buS1, buD + 2048);
    aS0 += BK; aS1 += BK; bgS0 += BK; bgS1 += BK; buS0 += BK; buS1 += BK;
    __syncthreads();

    bf16x8 af[4], bg[4], bu[4];
#pragma unroll
    for (int i = 0; i < 4; ++i)
      af[i] = *(const bf16x8*)&sA[(wm + i * 16 + mr) * BK + quad * 8];
#pragma unroll
    for (int j = 0; j < 4; ++j) {
      bg[j] = *(const bf16x8*)&sBg[(wn + j * 16 + mr) * BK + quad * 8];
      bu[j] = *(const bf16x8*)&sBu[(wn + j * 16 + mr) * BK + quad * 8];
    }
#pragma unroll
    for (int i = 0; i < 4; ++i)
#pragma unroll
      for (int j = 0; j < 4; ++j) {
        accg[i][j] = __builtin_amdgcn_mfma_f32_16x16x32_bf16(af[i], bg[j], accg[i][j], 0, 0, 0);
        accu[i][j] = __builtin_amdgcn_mfma_f32_16x16x32_bf16(af[i], bu[j], accu[i][j], 0, 0, 0);
      }
    __syncthreads();
  }

#pragma unroll
  for (int i = 0; i < 4; ++i)
#pragma unroll
    for (int j = 0; j < 4; ++j)
#pragma unroll
      for (int r = 0; r < 4; ++r) {
        const int m = wm + i * 16 + quad * 4 + r;
        const int n = wn + j * 16 + mr;
        const float gv = accg[i][j][r];
        const float uv = accu[i][j][r];
        const float s = gv / (1.f + __expf(-gv));
        act[(size_t)(base + m) * KTOT2 + (n0 + n)] = f2bf(s * uv);
      }
}

// ---------------- phase 2: down GEMM + weighted atomic combine ----------------
__global__ __launch_bounds__(256, 4)
void k_gemm2(const unsigned short* __restrict__ act, const unsigned short* __restrict__ w2x,
             const int* __restrict__ tok, const float* __restrict__ wgt,
             const int* __restrict__ pad_off, const int* __restrict__ cnt,
             float* __restrict__ out) {
  __shared__ __align__(16) unsigned short sA[BM * BK];
  __shared__ __align__(16) unsigned short sB[BN * BK];

  const int base = blockIdx.y * BM;
  if (base >= pad_off[E_]) return;
  int e = 0;
#pragma unroll
  for (int i = 1; i < E_; ++i) if (base >= pad_off[i]) e = i;
  const int erow0 = pad_off[e];
  const int cnt_e = cnt[e];
  const int n0 = blockIdx.x * BN;

  const int tid  = threadIdx.x;
  const int lane = tid & 63;
  const int wid  = tid >> 6;
  const int wm   = (wid >> 1) * 64;
  const int wn   = (wid & 1) * 64;
  const int quad = lane >> 4;
  const int mr   = lane & 15;

  const int srow = tid >> 2, spc = (tid & 3) * 8;
  const unsigned short* aS0 = act + (size_t)(base + srow) * KTOT2 + spc;
  const unsigned short* aS1 = aS0 + (size_t)64 * KTOT2;
  const unsigned short* bS0 = w2x + ((size_t)e * H_ + n0 + srow) * KTOT2 + spc;
  const unsigned short* bS1 = bS0 + (size_t)64 * KTOT2;
  unsigned short* aD = sA + wid * 512;
  unsigned short* bD = sB + wid * 512;

  f32x4 zero = {0.f, 0.f, 0.f, 0.f};
  f32x4 acc[4][4];
#pragma unroll
  for (int i = 0; i < 4; ++i)
#pragma unroll
    for (int j = 0; j < 4; ++j) acc[i][j] = zero;

  for (int kt = 0; kt < KTOT2; kt += BK) {
    async16(aS0, aD);  async16(aS1, aD + 2048);
    async16(bS0, bD);  async16(bS1, bD + 2048);
    aS0 += BK; aS1 += BK; bS0 += BK; bS1 += BK;
    __syncthreads();

    bf16x8 af[4], bb[4];
#pragma unroll
    for (int i = 0; i < 4; ++i)
      af[i] = *(const bf16x8*)&sA[(wm + i * 16 + mr) * BK + quad * 8];
#pragma unroll
    for (int j = 0; j < 4; ++j)
      bb[j] = *(const bf16x8*)&sB[(wn + j * 16 + mr) * BK + quad * 8];
#pragma unroll
    for (int i = 0; i < 4; ++i)
#pragma unroll
      for (int j = 0; j < 4; ++j)
        acc[i][j] = __builtin_amdgcn_mfma_f32_16x16x32_bf16(af[i], bb[j], acc[i][j], 0, 0, 0);
    __syncthreads();
  }

#pragma unroll
  for (int i = 0; i < 4; ++i)
#pragma unroll
    for (int j = 0; j < 4; ++j)
#pragma unroll
      for (int r = 0; r < 4; ++r) {
        const int m = wm + i * 16 + quad * 4 + r;
        const int g = base + m;
        if ((g - erow0) < cnt_e) {
          const int n = wn + j * 16 + mr;
          atomicAdd(&out[(size_t)tok[g] * H_ + (n0 + n)], wgt[g] * acc[i][j][r]);
        }
      }
}

extern "C" void kernel_launch(void* const* d_in, const int* in_sizes, int n_in,
                              void* d_out, int out_size, void* d_ws, size_t ws_size,
                              hipStream_t stream) {
  const float* hidden  = (const float*)d_in[0];
  const float* topk_w  = (const float*)d_in[1];
  const float* w13     = (const float*)d_in[2];
  const float* w2      = (const float*)d_in[3];
  const float* gua     = (const float*)d_in[4];
  const float* gub     = (const float*)d_in[5];
  const float* dna     = (const float*)d_in[6];
  const float* dnb     = (const float*)d_in[7];
  const int*   topk_id = (const int*)d_in[8];
  const int*   tli     = (const int*)d_in[9];
  float* out = (float*)d_out;

  char* ws = (char*)d_ws;
  int*   cnt     = (int*)(ws + 0);
  int*   cnt2    = (int*)(ws + 32);
  int*   pad_off = (int*)(ws + 64);
  size_t off = 256;
  int*   tok  = (int*)(ws + off);   off += 4 * MAXPAD;
  float* wgt  = (float*)(ws + off); off += 4 * MAXPAD;
  int*   lidx = (int*)(ws + off);   off += 4 * MAXPAD;
  unsigned short* x_rt  = (unsigned short*)(ws + off); off += (size_t)2 * MAXPAD * KTOT1;   // 38.9 MB
  unsigned short* act   = (unsigned short*)(ws + off); off += (size_t)2 * MAXPAD * KTOT2;   // 20.1 MB
  unsigned short* w13x  = (unsigned short*)(ws + off); off += (size_t)2 * E_ * I2_ * KTOT1; // 69.2 MB
  unsigned short* w2x   = (unsigned short*)(ws + off); off += (size_t)2 * E_ * H_ * KTOT2;  // 35.7 MB
  unsigned short* gua_x = (unsigned short*)(ws + off); off += (size_t)2 * E_ * LR_ * H_;    // 2.1 MB
  unsigned short* dna_x = (unsigned short*)(ws + off); off += (size_t)2 * E_ * LR_ * I_;    // 1.0 MB

  hipMemsetAsync(d_ws, 0, 256, stream);
  hipMemsetAsync(d_out, 0, (size_t)T_ * H_ * sizeof(float), stream);

  k_count  <<<dim3((T_ * K_ + 255) / 256), dim3(256), 0, stream>>>(topk_id, cnt);
  k_prefix <<<dim3(1), dim3(64), 0, stream>>>(cnt, pad_off);
  k_scatter<<<dim3((T_ * K_ + 255) / 256), dim3(256), 0, stream>>>(topk_id, topk_w, tli, pad_off,
                                                                   cnt2, tok, wgt, lidx);
  k_cvtA   <<<dim3(E_ * I2_ + E_ * LR_), dim3(256), 0, stream>>>(w13, gub, gua, w13x, gua_x);
  k_cvtB   <<<dim3(E_ * H_ + E_ * LR_), dim3(256), 0, stream>>>(w2, dnb, dna, w2x, dna_x);
  k_gather <<<dim3(MAXPAD), dim3(256), 0, stream>>>(hidden, tok, pad_off, cnt, x_rt);
  k_lora_gemm<H_, KTOT1, H_><<<dim3(MAXPAD / BM), dim3(256), 0, stream>>>(
      x_rt, gua_x, lidx, pad_off, cnt, x_rt);
  k_gemm1  <<<dim3(I_ / BN, MAXPAD / BM), dim3(256), 0, stream>>>(x_rt, w13x, pad_off, act);
  k_lora_gemm<I_, KTOT2, I_><<<dim3(MAXPAD / BM), dim3(256), 0, stream>>>(
      act, dna_x, lidx, pad_off, cnt, act);
  k_gemm2  <<<dim3(H_ / BN, MAXPAD / BM), dim3(256), 0, stream>>>(act, w2x, tok, wgt,
                                                                  pad_off, cnt, out);
}

// Round 4
// 694.943 us; speedup vs baseline: 2.0083x; 2.0083x over previous
//
#include <hip/hip_runtime.h>
#include <hip/hip_bf16.h>

// FusedMoEWithLoRA: grouped bf16-MFMA GEMMs, m97-style global_load_lds staging.
// LoRA B-matrices folded into GEMM K dim (K += L*R = 64); LoRA A-products
// computed as small MFMA GEMMs (u_all = X.gua^T, masked by adapter in epilogue).
// NOTE: k_gemm1/k_gemm2 MUST stay at __launch_bounds__(256,2) — the 4x4 dual
// accumulator needs ~164 regs; (256,4) forces 128 and spills ~2 GB to scratch
// (measured round 3: FETCH 1.3 GB, WRITE 1.98 GB, MfmaUtil 3.6%).

#define E_   8
#define H_   2048
#define I_   1024
#define I2_  2048
#define K_   2
#define L_   4
#define R_   16
#define T_   4096
#define LR_  64
#define BM   128
#define BN   128
#define BK   32
#define MAXPAD 9216
#define KTOT1 (H_ + LR_)   // 2112
#define KTOT2 (I_ + LR_)   // 1088

typedef __attribute__((ext_vector_type(8))) __bf16 bf16x8;
typedef __attribute__((ext_vector_type(4))) float  f32x4;

__device__ __forceinline__ unsigned short f2bf(float f) {
  union { float f; unsigned u; } v; v.f = f;
  unsigned u = v.u;
  u += 0x7fffu + ((u >> 16) & 1u);
  return (unsigned short)(u >> 16);
}
__device__ __forceinline__ unsigned pack2(float a, float b) {
  __hip_bfloat162 h = __float22bfloat162_rn(float2{a, b});
  union { __hip_bfloat162 h; unsigned u; } v; v.h = h;
  return v.u;
}
__device__ __forceinline__ void async16(const void* g, void* l) {
  __builtin_amdgcn_global_load_lds((const __attribute__((address_space(1))) void*)g,
                                   (__attribute__((address_space(3))) void*)l, 16, 0, 0);
}

// ---------------- routing ----------------
__global__ void k_count(const int* __restrict__ topk_ids, int* __restrict__ cnt) {
  int i = blockIdx.x * blockDim.x + threadIdx.x;
  if (i < T_ * K_) atomicAdd(&cnt[topk_ids[i]], 1);
}

__global__ void k_prefix(const int* __restrict__ cnt, int* __restrict__ pad_off) {
  if (threadIdx.x == 0) {
    int off = 0;
    for (int e = 0; e < E_; ++e) {
      pad_off[e] = off;
      off += ((cnt[e] + BM - 1) / BM) * BM;
    }
    pad_off[E_] = off;
  }
}

__global__ void k_scatter(const int* __restrict__ topk_ids, const float* __restrict__ topk_w,
                          const int* __restrict__ tli, const int* __restrict__ pad_off,
                          int* __restrict__ cnt2, int* __restrict__ tok,
                          float* __restrict__ wgt, int* __restrict__ lidx) {
  int i = blockIdx.x * blockDim.x + threadIdx.x;
  if (i < T_ * K_) {
    int e = topk_ids[i];
    int pos = atomicAdd(&cnt2[e], 1);
    int g = pad_off[e] + pos;
    int t = i / K_;
    tok[g] = t;
    wgt[g] = topk_w[i];
    lidx[g] = tli[t];
  }
}

// ---------------- bf16 conversions (K=2048 family): w13 + gub tail, gua ----------------
__global__ void k_cvtA(const float* __restrict__ w13, const float* __restrict__ gub,
                       const float* __restrict__ gua,
                       unsigned short* __restrict__ w13x, unsigned short* __restrict__ gua_x) {
  const int bid = blockIdx.x;
  const int tid = threadIdx.x;
  if (bid < E_ * I2_) {
    const int e = bid >> 11, n = bid & (I2_ - 1);
    const float* src = w13 + (size_t)bid * H_;
    unsigned short* dst = w13x + (size_t)bid * KTOT1;
#pragma unroll
    for (int c = tid; c < H_ / 4; c += 256) {
      float4 f = *(const float4*)(src + c * 4);
      *(uint2*)(dst + c * 4) = make_uint2(pack2(f.x, f.y), pack2(f.z, f.w));
    }
    if (tid < LR_) {
      const int l = tid >> 4, r = tid & 15;
      dst[H_ + tid] = f2bf(gub[(((size_t)l * E_ + e) * I2_ + n) * R_ + r]);
    }
  } else {
    const int idx = bid - E_ * I2_;               // e*64 + (l*16+r)
    const int e = idx >> 6, n = idx & 63;
    const int l = n >> 4, r = n & 15;
    const float* src = gua + (((size_t)l * E_ + e) * R_ + r) * H_;
    unsigned short* dst = gua_x + ((size_t)e * LR_ + n) * H_;
#pragma unroll
    for (int c = tid; c < H_ / 4; c += 256) {
      float4 f = *(const float4*)(src + c * 4);
      *(uint2*)(dst + c * 4) = make_uint2(pack2(f.x, f.y), pack2(f.z, f.w));
    }
  }
}

// ---------------- bf16 conversions (K=1024 family): w2 + dnb tail, dna ----------------
__global__ void k_cvtB(const float* __restrict__ w2, const float* __restrict__ dnb,
                       const float* __restrict__ dna,
                       unsigned short* __restrict__ w2x, unsigned short* __restrict__ dna_x) {
  const int bid = blockIdx.x;
  const int tid = threadIdx.x;
  if (bid < E_ * H_) {
    const int e = bid >> 11, n = bid & (H_ - 1);
    const float* src = w2 + (size_t)bid * I_;
    unsigned short* dst = w2x + (size_t)bid * KTOT2;
    {
      float4 f = *(const float4*)(src + tid * 4);
      *(uint2*)(dst + tid * 4) = make_uint2(pack2(f.x, f.y), pack2(f.z, f.w));
    }
    if (tid < LR_) {
      const int l = tid >> 4, r = tid & 15;
      dst[I_ + tid] = f2bf(dnb[(((size_t)l * E_ + e) * H_ + n) * R_ + r]);
    }
  } else {
    const int idx = bid - E_ * H_;
    const int e = idx >> 6, n = idx & 63;
    const int l = n >> 4, r = n & 15;
    const float* src = dna + (((size_t)l * E_ + e) * R_ + r) * I_;
    unsigned short* dst = dna_x + ((size_t)e * LR_ + n) * I_;
    {
      float4 f = *(const float4*)(src + tid * 4);
      *(uint2*)(dst + tid * 4) = make_uint2(pack2(f.x, f.y), pack2(f.z, f.w));
    }
  }
}

// ---------------- gather hidden rows into routed order (bf16) ----------------
__global__ void k_gather(const float* __restrict__ hidden, const int* __restrict__ tok,
                         const int* __restrict__ pad_off, const int* __restrict__ cnt,
                         unsigned short* __restrict__ x_rt) {
  const int g = blockIdx.x;
  const int tid = threadIdx.x;
  int e = -1;
#pragma unroll
  for (int i = 0; i < E_; ++i)
    if (g >= pad_off[i] && g < pad_off[i + 1]) e = i;
  const bool valid = (e >= 0) && ((g - pad_off[e]) < cnt[e]);
  const int t = valid ? tok[g] : 0;
  const float* src = hidden + (size_t)t * H_;
  unsigned short* dst = x_rt + (size_t)g * KTOT1;
#pragma unroll
  for (int c = tid; c < H_ / 4; c += 256) {
    uint2 v = make_uint2(0u, 0u);
    if (valid) {
      float4 f = *(const float4*)(src + c * 4);
      v = make_uint2(pack2(f.x, f.y), pack2(f.z, f.w));
    }
    *(uint2*)(dst + c * 4) = v;
  }
}

// ---------------- LoRA-A GEMM: strip[g][n] = (n>>4 == lidx[g]) ? X[g]·A[n] : 0 ----------------
template <int KDIM, int RSTRIDE, int KOFS>
__global__ __launch_bounds__(256, 4)
void k_lora_gemm(const unsigned short* __restrict__ X, const unsigned short* __restrict__ A,
                 const int* __restrict__ lidx, const int* __restrict__ pad_off,
                 const int* __restrict__ cnt, unsigned short* __restrict__ dst) {
  __shared__ __align__(16) unsigned short sA[BM * BK];   // 8 KB
  __shared__ __align__(16) unsigned short sB[LR_ * BK];  // 4 KB

  const int base = blockIdx.x * BM;
  if (base >= pad_off[E_]) return;
  int e = 0;
#pragma unroll
  for (int i = 1; i < E_; ++i) if (base >= pad_off[i]) e = i;
  const int erow0 = pad_off[e];
  const int cnt_e = cnt[e];

  const int tid  = threadIdx.x;
  const int lane = tid & 63;
  const int wid  = tid >> 6;
  const int wm   = wid * 32;
  const int quad = lane >> 4;
  const int mr   = lane & 15;

  const unsigned short* aS0 = X + (size_t)(base + (tid >> 2)) * RSTRIDE + (tid & 3) * 8;
  const unsigned short* aS1 = aS0 + (size_t)64 * RSTRIDE;
  const unsigned short* bS  = A + ((size_t)e * LR_ + (tid >> 2)) * KDIM + (tid & 3) * 8;
  unsigned short* aD = sA + wid * 512;
  unsigned short* bD = sB + wid * 512;

  f32x4 zero = {0.f, 0.f, 0.f, 0.f};
  f32x4 acc[2][4];
#pragma unroll
  for (int i = 0; i < 2; ++i)
#pragma unroll
    for (int j = 0; j < 4; ++j) acc[i][j] = zero;

  for (int kt = 0; kt < KDIM; kt += BK) {
    async16(aS0, aD);  async16(aS1, aD + 2048);
    async16(bS,  bD);
    aS0 += BK; aS1 += BK; bS += BK;
    __syncthreads();

    bf16x8 af[2], bb[4];
#pragma unroll
    for (int i = 0; i < 2; ++i)
      af[i] = *(const bf16x8*)&sA[(wm + i * 16 + mr) * BK + quad * 8];
#pragma unroll
    for (int j = 0; j < 4; ++j)
      bb[j] = *(const bf16x8*)&sB[(j * 16 + mr) * BK + quad * 8];
#pragma unroll
    for (int i = 0; i < 2; ++i)
#pragma unroll
      for (int j = 0; j < 4; ++j)
        acc[i][j] = __builtin_amdgcn_mfma_f32_16x16x32_bf16(af[i], bb[j], acc[i][j], 0, 0, 0);
    __syncthreads();
  }

  // epilogue: column n = j*16+mr encodes adapter l = j; mask and store strip.
#pragma unroll
  for (int i = 0; i < 2; ++i)
#pragma unroll
    for (int j = 0; j < 4; ++j)
#pragma unroll
      for (int r = 0; r < 4; ++r) {
        const int m = wm + i * 16 + quad * 4 + r;
        const int g = base + m;
        const bool valid = ((g - erow0) < cnt_e) && (lidx[g] == j);
        const float v = valid ? acc[i][j][r] : 0.f;
        dst[(size_t)g * RSTRIDE + KOFS + j * 16 + mr] = f2bf(v);
      }
}

// ---------------- phase 1: gate_up GEMM + SwiGLU ----------------
__global__ __launch_bounds__(256, 2)
void k_gemm1(const unsigned short* __restrict__ x_rt, const unsigned short* __restrict__ w13x,
             const int* __restrict__ pad_off, unsigned short* __restrict__ act) {
  __shared__ __align__(16) unsigned short sA [BM * BK];
  __shared__ __align__(16) unsigned short sBg[BN * BK];
  __shared__ __align__(16) unsigned short sBu[BN * BK];

  const int base = blockIdx.y * BM;
  if (base >= pad_off[E_]) return;
  int e = 0;
#pragma unroll
  for (int i = 1; i < E_; ++i) if (base >= pad_off[i]) e = i;
  const int n0 = blockIdx.x * BN;

  const int tid  = threadIdx.x;
  const int lane = tid & 63;
  const int wid  = tid >> 6;
  const int wm   = (wid >> 1) * 64;
  const int wn   = (wid & 1) * 64;
  const int quad = lane >> 4;
  const int mr   = lane & 15;

  const int srow = tid >> 2, spc = (tid & 3) * 8;
  const unsigned short* aS0  = x_rt + (size_t)(base + srow) * KTOT1 + spc;
  const unsigned short* aS1  = aS0 + (size_t)64 * KTOT1;
  const unsigned short* bgS0 = w13x + ((size_t)e * I2_ + n0 + srow) * KTOT1 + spc;
  const unsigned short* bgS1 = bgS0 + (size_t)64 * KTOT1;
  const unsigned short* buS0 = bgS0 + (size_t)I_ * KTOT1;
  const unsigned short* buS1 = buS0 + (size_t)64 * KTOT1;
  unsigned short* aD  = sA  + wid * 512;
  unsigned short* bgD = sBg + wid * 512;
  unsigned short* buD = sBu + wid * 512;

  f32x4 zero = {0.f, 0.f, 0.f, 0.f};
  f32x4 accg[4][4], accu[4][4];
#pragma unroll
  for (int i = 0; i < 4; ++i)
#pragma unroll
    for (int j = 0; j < 4; ++j) { accg[i][j] = zero; accu[i][j] = zero; }

  for (int kt = 0; kt < KTOT1; kt += BK) {
    async16(aS0,  aD);        async16(aS1,  aD + 2048);
    async16(bgS0, bgD);       async16(bgS1, bgD + 2048);
    async16(buS0, buD);       async16(buS1, buD + 2048);
    aS0 += BK; aS1 += BK; bgS0 += BK; bgS1 += BK; buS0 += BK; buS1 += BK;
    __syncthreads();

    bf16x8 af[4], bg[4], bu[4];
#pragma unroll
    for (int i = 0; i < 4; ++i)
      af[i] = *(const bf16x8*)&sA[(wm + i * 16 + mr) * BK + quad * 8];
#pragma unroll
    for (int j = 0; j < 4; ++j) {
      bg[j] = *(const bf16x8*)&sBg[(wn + j * 16 + mr) * BK + quad * 8];
      bu[j] = *(const bf16x8*)&sBu[(wn + j * 16 + mr) * BK + quad * 8];
    }
#pragma unroll
    for (int i = 0; i < 4; ++i)
#pragma unroll
      for (int j = 0; j < 4; ++j) {
        accg[i][j] = __builtin_amdgcn_mfma_f32_16x16x32_bf16(af[i], bg[j], accg[i][j], 0, 0, 0);
        accu[i][j] = __builtin_amdgcn_mfma_f32_16x16x32_bf16(af[i], bu[j], accu[i][j], 0, 0, 0);
      }
    __syncthreads();
  }

#pragma unroll
  for (int i = 0; i < 4; ++i)
#pragma unroll
    for (int j = 0; j < 4; ++j)
#pragma unroll
      for (int r = 0; r < 4; ++r) {
        const int m = wm + i * 16 + quad * 4 + r;
        const int n = wn + j * 16 + mr;
        const float gv = accg[i][j][r];
        const float uv = accu[i][j][r];
        const float s = gv / (1.f + __expf(-gv));
        act[(size_t)(base + m) * KTOT2 + (n0 + n)] = f2bf(s * uv);
      }
}

// ---------------- phase 2: down GEMM + weighted atomic combine ----------------
__global__ __launch_bounds__(256, 2)
void k_gemm2(const unsigned short* __restrict__ act, const unsigned short* __restrict__ w2x,
             const int* __restrict__ tok, const float* __restrict__ wgt,
             const int* __restrict__ pad_off, const int* __restrict__ cnt,
             float* __restrict__ out) {
  __shared__ __align__(16) unsigned short sA[BM * BK];
  __shared__ __align__(16) unsigned short sB[BN * BK];

  const int base = blockIdx.y * BM;
  if (base >= pad_off[E_]) return;
  int e = 0;
#pragma unroll
  for (int i = 1; i < E_; ++i) if (base >= pad_off[i]) e = i;
  const int erow0 = pad_off[e];
  const int cnt_e = cnt[e];
  const int n0 = blockIdx.x * BN;

  const int tid  = threadIdx.x;
  const int lane = tid & 63;
  const int wid  = tid >> 6;
  const int wm   = (wid >> 1) * 64;
  const int wn   = (wid & 1) * 64;
  const int quad = lane >> 4;
  const int mr   = lane & 15;

  const int srow = tid >> 2, spc = (tid & 3) * 8;
  const unsigned short* aS0 = act + (size_t)(base + srow) * KTOT2 + spc;
  const unsigned short* aS1 = aS0 + (size_t)64 * KTOT2;
  const unsigned short* bS0 = w2x + ((size_t)e * H_ + n0 + srow) * KTOT2 + spc;
  const unsigned short* bS1 = bS0 + (size_t)64 * KTOT2;
  unsigned short* aD = sA + wid * 512;
  unsigned short* bD = sB + wid * 512;

  f32x4 zero = {0.f, 0.f, 0.f, 0.f};
  f32x4 acc[4][4];
#pragma unroll
  for (int i = 0; i < 4; ++i)
#pragma unroll
    for (int j = 0; j < 4; ++j) acc[i][j] = zero;

  for (int kt = 0; kt < KTOT2; kt += BK) {
    async16(aS0, aD);  async16(aS1, aD + 2048);
    async16(bS0, bD);  async16(bS1, bD + 2048);
    aS0 += BK; aS1 += BK; bS0 += BK; bS1 += BK;
    __syncthreads();

    bf16x8 af[4], bb[4];
#pragma unroll
    for (int i = 0; i < 4; ++i)
      af[i] = *(const bf16x8*)&sA[(wm + i * 16 + mr) * BK + quad * 8];
#pragma unroll
    for (int j = 0; j < 4; ++j)
      bb[j] = *(const bf16x8*)&sB[(wn + j * 16 + mr) * BK + quad * 8];
#pragma unroll
    for (int i = 0; i < 4; ++i)
#pragma unroll
      for (int j = 0; j < 4; ++j)
        acc[i][j] = __builtin_amdgcn_mfma_f32_16x16x32_bf16(af[i], bb[j], acc[i][j], 0, 0, 0);
    __syncthreads();
  }

#pragma unroll
  for (int i = 0; i < 4; ++i)
#pragma unroll
    for (int j = 0; j < 4; ++j)
#pragma unroll
      for (int r = 0; r < 4; ++r) {
        const int m = wm + i * 16 + quad * 4 + r;
        const int g = base + m;
        if ((g - erow0) < cnt_e) {
          const int n = wn + j * 16 + mr;
          atomicAdd(&out[(size_t)tok[g] * H_ + (n0 + n)], wgt[g] * acc[i][j][r]);
        }
      }
}

extern "C" void kernel_launch(void* const* d_in, const int* in_sizes, int n_in,
                              void* d_out, int out_size, void* d_ws, size_t ws_size,
                              hipStream_t stream) {
  const float* hidden  = (const float*)d_in[0];
  const float* topk_w  = (const float*)d_in[1];
  const float* w13     = (const float*)d_in[2];
  const float* w2      = (const float*)d_in[3];
  const float* gua     = (const float*)d_in[4];
  const float* gub     = (const float*)d_in[5];
  const float* dna     = (const float*)d_in[6];
  const float* dnb     = (const float*)d_in[7];
  const int*   topk_id = (const int*)d_in[8];
  const int*   tli     = (const int*)d_in[9];
  float* out = (float*)d_out;

  char* ws = (char*)d_ws;
  int*   cnt     = (int*)(ws + 0);
  int*   cnt2    = (int*)(ws + 32);
  int*   pad_off = (int*)(ws + 64);
  size_t off = 256;
  int*   tok  = (int*)(ws + off);   off += 4 * MAXPAD;
  float* wgt  = (float*)(ws + off); off += 4 * MAXPAD;
  int*   lidx = (int*)(ws + off);   off += 4 * MAXPAD;
  unsigned short* x_rt  = (unsigned short*)(ws + off); off += (size_t)2 * MAXPAD * KTOT1;   // 38.9 MB
  unsigned short* act   = (unsigned short*)(ws + off); off += (size_t)2 * MAXPAD * KTOT2;   // 20.1 MB
  unsigned short* w13x  = (unsigned short*)(ws + off); off += (size_t)2 * E_ * I2_ * KTOT1; // 69.2 MB
  unsigned short* w2x   = (unsigned short*)(ws + off); off += (size_t)2 * E_ * H_ * KTOT2;  // 35.7 MB
  unsigned short* gua_x = (unsigned short*)(ws + off); off += (size_t)2 * E_ * LR_ * H_;    // 2.1 MB
  unsigned short* dna_x = (unsigned short*)(ws + off); off += (size_t)2 * E_ * LR_ * I_;    // 1.0 MB

  hipMemsetAsync(d_ws, 0, 256, stream);
  hipMemsetAsync(d_out, 0, (size_t)T_ * H_ * sizeof(float), stream);

  k_count  <<<dim3((T_ * K_ + 255) / 256), dim3(256), 0, stream>>>(topk_id, cnt);
  k_prefix <<<dim3(1), dim3(64), 0, stream>>>(cnt, pad_off);
  k_scatter<<<dim3((T_ * K_ + 255) / 256), dim3(256), 0, stream>>>(topk_id, topk_w, tli, pad_off,
                                                                   cnt2, tok, wgt, lidx);
  k_cvtA   <<<dim3(E_ * I2_ + E_ * LR_), dim3(256), 0, stream>>>(w13, gub, gua, w13x, gua_x);
  k_cvtB   <<<dim3(E_ * H_ + E_ * LR_), dim3(256), 0, stream>>>(w2, dnb, dna, w2x, dna_x);
  k_gather <<<dim3(MAXPAD), dim3(256), 0, stream>>>(hidden, tok, pad_off, cnt, x_rt);
  k_lora_gemm<H_, KTOT1, H_><<<dim3(MAXPAD / BM), dim3(256), 0, stream>>>(
      x_rt, gua_x, lidx, pad_off, cnt, x_rt);
  k_gemm1  <<<dim3(I_ / BN, MAXPAD / BM), dim3(256), 0, stream>>>(x_rt, w13x, pad_off, act);
  k_lora_gemm<I_, KTOT2, I_><<<dim3(MAXPAD / BM), dim3(256), 0, stream>>>(
      act, dna_x, lidx, pad_off, cnt, act);
  k_gemm2  <<<dim3(H_ / BN, MAXPAD / BM), dim3(256), 0, stream>>>(act, w2x, tok, wgt,
                                                                  pad_off, cnt, out);
}